// Round 2
// baseline (251.798 us; speedup 1.0000x reference)
//
#include <hip/hip_runtime.h>
#include <hip/hip_bf16.h>

#define S_LEN 2048
#define D_DIM 64
#define NB 16

// exp(x/sqrt(64)) = exp2(x * log2(e)/8)
#define C_EXP 0.1803368801111204f

typedef __attribute__((ext_vector_type(8))) __bf16 bf16x8;
typedef __attribute__((ext_vector_type(4))) __bf16 bf16x4;
typedef __attribute__((ext_vector_type(4))) float f32x4;

// ---------------------------------------------------------------------------
// Kernel A: convert Q and K fp32 -> bf16 (vectorized float4 -> bf16x4)
// ---------------------------------------------------------------------------
__global__ __launch_bounds__(256) void convert_bf16_kernel(
    const float* __restrict__ qf, const float* __restrict__ kf,
    __bf16* __restrict__ qb, __bf16* __restrict__ kb) {
  const int n4 = NB * S_LEN * D_DIM / 4;
  for (int i = blockIdx.x * blockDim.x + threadIdx.x; i < n4;
       i += gridDim.x * blockDim.x) {
    float4 a = ((const float4*)qf)[i];
    float4 c = ((const float4*)kf)[i];
    bf16x4 oa = {(__bf16)a.x, (__bf16)a.y, (__bf16)a.z, (__bf16)a.w};
    bf16x4 oc = {(__bf16)c.x, (__bf16)c.y, (__bf16)c.z, (__bf16)c.w};
    ((bf16x4*)qb)[i] = oa;
    ((bf16x4*)kb)[i] = oc;
  }
}

// ---------------------------------------------------------------------------
// Kernel B: column stats. L[b,k] = sum_q exp(S[q,k]) computed as row-sums of
// exp(K·Q^T/8). One wg per (k-block of 64, b); wave handles 16 k-rows.
// A-frag (K rows) is loop-invariant -> preloaded in registers.
// ---------------------------------------------------------------------------
__global__ __launch_bounds__(256) void stats_kernel(
    const __bf16* __restrict__ Qb, const __bf16* __restrict__ Kb,
    float* __restrict__ L) {
  const int b = blockIdx.y;
  const int kblk = blockIdx.x;              // 0..31
  const int wave = threadIdx.x >> 6;        // 0..3
  const int lane = threadIdx.x & 63;
  const int l16 = lane & 15;
  const int g = lane >> 4;

  const int kbase = kblk * 64 + wave * 16;
  const __bf16* kp = Kb + ((size_t)b * S_LEN + kbase + l16) * D_DIM + g * 8;
  bf16x8 ak0 = *(const bf16x8*)(kp);
  bf16x8 ak1 = *(const bf16x8*)(kp + 32);

  float sacc[4] = {0.f, 0.f, 0.f, 0.f};
  const __bf16* Qbase = Qb + (size_t)b * S_LEN * D_DIM;

  for (int q0 = 0; q0 < S_LEN; q0 += 64) {
#pragma unroll
    for (int qt = 0; qt < 4; ++qt) {
      const __bf16* qp = Qbase + (size_t)(q0 + qt * 16 + l16) * D_DIM + g * 8;
      bf16x8 bq0 = *(const bf16x8*)(qp);
      bf16x8 bq1 = *(const bf16x8*)(qp + 32);
      f32x4 t = __builtin_amdgcn_mfma_f32_16x16x32_bf16(
          ak0, bq0, (f32x4){0.f, 0.f, 0.f, 0.f}, 0, 0, 0);
      t = __builtin_amdgcn_mfma_f32_16x16x32_bf16(ak1, bq1, t, 0, 0, 0);
#pragma unroll
      for (int r = 0; r < 4; ++r)
        sacc[r] += __builtin_amdgcn_exp2f(t[r] * C_EXP);
    }
  }
  // reduce across the 16 q-columns held by lanes sharing the same g
#pragma unroll
  for (int r = 0; r < 4; ++r) {
    float v = sacc[r];
    v += __shfl_xor(v, 1);
    v += __shfl_xor(v, 2);
    v += __shfl_xor(v, 4);
    v += __shfl_xor(v, 8);
    if (l16 == 0) L[(size_t)b * S_LEN + kbase + g * 4 + r] = v;
  }
}

// ---------------------------------------------------------------------------
// Kernel C: Vt[b][d][k] = bf16(V[b][k][d] / L[b][k])  (transposed + scaled)
// thread t owns k = blk*256+t; writes along k are coalesced.
// ---------------------------------------------------------------------------
__global__ __launch_bounds__(256) void scalev_kernel(
    const float* __restrict__ V, const float* __restrict__ L,
    __bf16* __restrict__ Vt) {
  const int b = blockIdx.y;
  const int k = blockIdx.x * 256 + threadIdx.x;
  const float inv = 1.0f / L[(size_t)b * S_LEN + k];
  const float* vrow = V + ((size_t)b * S_LEN + k) * D_DIM;
  __bf16* vt = Vt + (size_t)b * D_DIM * S_LEN + k;
#pragma unroll
  for (int d = 0; d < D_DIM; ++d)
    vt[(size_t)d * S_LEN] = (__bf16)(vrow[d] * inv);
}

// ---------------------------------------------------------------------------
// Kernel D: Out = exp(Q·K^T/8) @ Vt.  One wg per (q-block of 64, b);
// wave handles 16 q-rows x 64 d.  P goes through a per-wave LDS buffer to
// convert the MFMA C/D layout into the A-operand layout (no cross-wave sync).
// ---------------------------------------------------------------------------
__global__ __launch_bounds__(256) void attn_out_kernel(
    const __bf16* __restrict__ Qb, const __bf16* __restrict__ Kb,
    const __bf16* __restrict__ Vt, float* __restrict__ Out) {
  __shared__ __bf16 Plds[4][16][72];  // stride 144B: 16B-aligned, bank-spread
  const int b = blockIdx.y;
  const int qblk = blockIdx.x;
  const int wave = threadIdx.x >> 6;
  const int lane = threadIdx.x & 63;
  const int l16 = lane & 15;
  const int g = lane >> 4;

  const int qbase = qblk * 64 + wave * 16;
  const __bf16* qp = Qb + ((size_t)b * S_LEN + qbase + l16) * D_DIM + g * 8;
  bf16x8 aq0 = *(const bf16x8*)(qp);
  bf16x8 aq1 = *(const bf16x8*)(qp + 32);

  f32x4 acc[4] = {};
  const __bf16* Kbase = Kb + (size_t)b * S_LEN * D_DIM;
  const __bf16* Vbase = Vt + (size_t)b * D_DIM * S_LEN;
  __bf16(*pl)[72] = Plds[wave];

  for (int k0 = 0; k0 < S_LEN; k0 += 64) {
    // --- S tile (16 q x 64 k) + exp -> P in LDS ---
#pragma unroll
    for (int kt = 0; kt < 4; ++kt) {
      const __bf16* kp = Kbase + (size_t)(k0 + kt * 16 + l16) * D_DIM + g * 8;
      bf16x8 bk0 = *(const bf16x8*)(kp);
      bf16x8 bk1 = *(const bf16x8*)(kp + 32);
      f32x4 t = __builtin_amdgcn_mfma_f32_16x16x32_bf16(
          aq0, bk0, (f32x4){0.f, 0.f, 0.f, 0.f}, 0, 0, 0);
      t = __builtin_amdgcn_mfma_f32_16x16x32_bf16(aq1, bk1, t, 0, 0, 0);
#pragma unroll
      for (int r = 0; r < 4; ++r)
        pl[g * 4 + r][kt * 16 + l16] =
            (__bf16)__builtin_amdgcn_exp2f(t[r] * C_EXP);
    }
    // --- read P back as A-fragments (wave-private: no barrier needed) ---
    bf16x8 pa0 = *(const bf16x8*)(&pl[l16][g * 8]);
    bf16x8 pa1 = *(const bf16x8*)(&pl[l16][32 + g * 8]);
    // --- PV: acc[dt] += P @ Vt ---
#pragma unroll
    for (int dt = 0; dt < 4; ++dt) {
      const __bf16* vp = Vbase + (size_t)(dt * 16 + l16) * S_LEN + k0 + g * 8;
      bf16x8 bv0 = *(const bf16x8*)(vp);
      bf16x8 bv1 = *(const bf16x8*)(vp + 32);
      acc[dt] = __builtin_amdgcn_mfma_f32_16x16x32_bf16(pa0, bv0, acc[dt], 0, 0, 0);
      acc[dt] = __builtin_amdgcn_mfma_f32_16x16x32_bf16(pa1, bv1, acc[dt], 0, 0, 0);
    }
  }
  // epilogue: C/D layout -> Out[b][q][d] fp32
  float* obase = Out + (size_t)b * S_LEN * D_DIM;
#pragma unroll
  for (int dt = 0; dt < 4; ++dt)
#pragma unroll
    for (int r = 0; r < 4; ++r)
      obase[(size_t)(qbase + g * 4 + r) * D_DIM + dt * 16 + l16] = acc[dt][r];
}

// ---------------------------------------------------------------------------
extern "C" void kernel_launch(void* const* d_in, const int* in_sizes, int n_in,
                              void* d_out, int out_size, void* d_ws,
                              size_t ws_size, hipStream_t stream) {
  const float* q = (const float*)d_in[0];
  const float* k = (const float*)d_in[1];
  const float* v = (const float*)d_in[2];
  float* out = (float*)d_out;

  char* ws = (char*)d_ws;
  const size_t nelem = (size_t)NB * S_LEN * D_DIM;  // 2,097,152
  __bf16* Qb = (__bf16*)ws;                          // 4 MB
  __bf16* Kb = (__bf16*)(ws + nelem * 2);            // 4 MB
  __bf16* Vt = (__bf16*)(ws + nelem * 4);            // 4 MB
  float* L = (float*)(ws + nelem * 6);               // 128 KB

  convert_bf16_kernel<<<1024, 256, 0, stream>>>(q, k, Qb, Kb);
  stats_kernel<<<dim3(32, 16), 256, 0, stream>>>(Qb, Kb, L);
  scalev_kernel<<<dim3(8, 16), 256, 0, stream>>>(v, L, Vt);
  attn_out_kernel<<<dim3(32, 16), 256, 0, stream>>>(Qb, Kb, Vt, out);
}

// Round 6
// 134.483 us; speedup vs baseline: 1.8723x; 1.8723x over previous
//
#include <hip/hip_runtime.h>
#include <hip/hip_bf16.h>

#define S_LEN 2048
#define D_DIM 64
#define NB 16

// exp(x/sqrt(64)) = exp2(x * log2(e)/8)
#define C_EXP 0.1803368801111204f

typedef __attribute__((ext_vector_type(8))) __bf16 bf16x8;
typedef __attribute__((ext_vector_type(4))) __bf16 bf16x4;
typedef __attribute__((ext_vector_type(4))) float f32x4;

// global -> LDS direct DMA, 16B per lane. Per-thread lds dest must be
// base + tid*16 (HW writes wave-uniform base + lane*16).
#define GLOAD16(gp, lp)                                              \
  __builtin_amdgcn_global_load_lds(                                  \
      (const __attribute__((address_space(1))) void*)(gp),           \
      (__attribute__((address_space(3))) void*)(lp), 16, 0, 0)

// ---------------------------------------------------------------------------
// Kernel A: convert Q and K fp32 -> bf16
// ---------------------------------------------------------------------------
__global__ __launch_bounds__(256) void convert_bf16_kernel(
    const float* __restrict__ qf, const float* __restrict__ kf,
    __bf16* __restrict__ qb, __bf16* __restrict__ kb) {
  const int n4 = NB * S_LEN * D_DIM / 4;
  for (int i = blockIdx.x * blockDim.x + threadIdx.x; i < n4;
       i += gridDim.x * blockDim.x) {
    float4 a = ((const float4*)qf)[i];
    float4 c = ((const float4*)kf)[i];
    bf16x4 oa = {(__bf16)a.x, (__bf16)a.y, (__bf16)a.z, (__bf16)a.w};
    bf16x4 oc = {(__bf16)c.x, (__bf16)c.y, (__bf16)c.z, (__bf16)c.w};
    ((bf16x4*)qb)[i] = oa;
    ((bf16x4*)kb)[i] = oc;
  }
}

// ---------------------------------------------------------------------------
// Kernel B: partial column stats over a q-range.
// Lpart[qs][b][k] = sum_{q in range} exp(S[q,k]).  Q tiles staged in LDS
// (XOR-swizzled via pre-swizzled global source) and shared by all 4 waves.
// ---------------------------------------------------------------------------
__global__ __launch_bounds__(256) void stats_kernel(
    const __bf16* __restrict__ Qb, const __bf16* __restrict__ Kb,
    float* __restrict__ Lpart, int qlen) {
  __shared__ __align__(16) __bf16 QT[4096];  // 64 rows x 64 cols, swizzled
  const int b = blockIdx.y;
  const int kblk = blockIdx.x;
  const int qs = blockIdx.z;
  const int tid = threadIdx.x;
  const int wave = tid >> 6;
  const int lane = tid & 63;
  const int l16 = lane & 15;
  const int g = lane >> 4;

  const int kbase = kblk * 64 + wave * 16;
  const __bf16* kp = Kb + ((size_t)b * S_LEN + kbase + l16) * D_DIM + g * 8;
  bf16x8 ak0 = *(const bf16x8*)(kp);
  bf16x8 ak1 = *(const bf16x8*)(kp + 32);

  // staging source: thread covers LDS row (h*32 + tid>>3), swizzled col
  const int srow = tid >> 3;                       // 0..31
  const int scol = 8 * ((tid & 7) ^ (srow & 7));   // pre-swizzled global col

  float sacc[4] = {0.f, 0.f, 0.f, 0.f};
  const __bf16* Qbase = Qb + (size_t)b * S_LEN * D_DIM;
  const int qbeg = qs * qlen;

  for (int q0 = qbeg; q0 < qbeg + qlen; q0 += 64) {
    __syncthreads();  // protect QT until all waves finished previous tile
#pragma unroll
    for (int h = 0; h < 2; ++h)
      GLOAD16(Qbase + (size_t)(q0 + h * 32 + srow) * D_DIM + scol,
              (char*)QT + h * 4096 + (size_t)tid * 16);
    asm volatile("s_waitcnt vmcnt(0)" ::: "memory");
    __syncthreads();

#pragma unroll
    for (int qt = 0; qt < 4; ++qt) {
      const int r = qt * 16 + l16;
      bf16x8 bq0 = *(const bf16x8*)(QT + r * 64 + 8 * (g ^ (r & 7)));
      bf16x8 bq1 = *(const bf16x8*)(QT + r * 64 + 8 * ((g + 4) ^ (r & 7)));
      f32x4 t = __builtin_amdgcn_mfma_f32_16x16x32_bf16(
          ak0, bq0, (f32x4){0.f, 0.f, 0.f, 0.f}, 0, 0, 0);
      t = __builtin_amdgcn_mfma_f32_16x16x32_bf16(ak1, bq1, t, 0, 0, 0);
#pragma unroll
      for (int r4 = 0; r4 < 4; ++r4)
        sacc[r4] += __builtin_amdgcn_exp2f(t[r4] * C_EXP);
    }
  }
#pragma unroll
  for (int r4 = 0; r4 < 4; ++r4) {
    float v = sacc[r4];
    v += __shfl_xor(v, 1);
    v += __shfl_xor(v, 2);
    v += __shfl_xor(v, 4);
    v += __shfl_xor(v, 8);
    if (l16 == 0)
      Lpart[(size_t)qs * NB * S_LEN + (size_t)b * S_LEN + kbase + g * 4 + r4] =
          v;
  }
}

// ---------------------------------------------------------------------------
// Kernel C: Vt[b][d][k] = bf16(V[b][k][d] / L[b][k]),  L = sum of 4 partials
// ---------------------------------------------------------------------------
__global__ __launch_bounds__(256) void scalev_kernel(
    const float* __restrict__ V, const float* __restrict__ Lpart,
    __bf16* __restrict__ Vt) {
  const int b = blockIdx.y;
  const int k = blockIdx.x * 256 + threadIdx.x;
  const size_t NS = (size_t)NB * S_LEN;
  const size_t idx = (size_t)b * S_LEN + k;
  const float L =
      Lpart[idx] + Lpart[NS + idx] + Lpart[2 * NS + idx] + Lpart[3 * NS + idx];
  const float inv = 1.0f / L;
  const float* vrow = V + ((size_t)b * S_LEN + k) * D_DIM;
  __bf16* vt = Vt + (size_t)b * D_DIM * S_LEN + k;
#pragma unroll
  for (int d = 0; d < D_DIM; ++d)
    vt[(size_t)d * S_LEN] = (__bf16)(vrow[d] * inv);
}

// ---------------------------------------------------------------------------
// Kernel D: partial Out = exp(Q·K^T/8) @ Vt over a k-range (split-k).
// Each ks-slab gets its own output region: Op + (ks*NB + b)*S*D.
// K and Vt tiles staged in LDS via global_load_lds with pre-swizzled source;
// fragment ds_read_b128s are bank-conflict-free.
// ---------------------------------------------------------------------------
__global__ __launch_bounds__(256) void attn_out_kernel(
    const __bf16* __restrict__ Qb, const __bf16* __restrict__ Kb,
    const __bf16* __restrict__ Vt, float* __restrict__ Op, int klen) {
  __shared__ __align__(16) __bf16 KT[4096];   // 64 k-rows x 64 d, swizzled
  __shared__ __align__(16) __bf16 VT[4096];   // 64 d-rows x 64 k, swizzled
  __shared__ __align__(16) __bf16 Plds[4][16][72];
  const int b = blockIdx.y;
  const int qblk = blockIdx.x;
  const int ks = blockIdx.z;
  const int tid = threadIdx.x;
  const int wave = tid >> 6;
  const int lane = tid & 63;
  const int l16 = lane & 15;
  const int g = lane >> 4;

  const int qbase = qblk * 64 + wave * 16;
  const __bf16* qp = Qb + ((size_t)b * S_LEN + qbase + l16) * D_DIM + g * 8;
  bf16x8 aq0 = *(const bf16x8*)(qp);
  bf16x8 aq1 = *(const bf16x8*)(qp + 32);

  f32x4 acc[4] = {};
  const int srow = tid >> 3;
  const int scol = 8 * ((tid & 7) ^ (srow & 7));
  const __bf16* Kbase = Kb + (size_t)b * S_LEN * D_DIM;
  const __bf16* Vbase = Vt + (size_t)b * D_DIM * S_LEN;
  __bf16(*pl)[72] = Plds[wave];
  const int kbeg = ks * klen;

  for (int k0 = kbeg; k0 < kbeg + klen; k0 += 64) {
    __syncthreads();
#pragma unroll
    for (int h = 0; h < 2; ++h) {
      GLOAD16(Kbase + (size_t)(k0 + h * 32 + srow) * D_DIM + scol,
              (char*)KT + h * 4096 + (size_t)tid * 16);
      GLOAD16(Vbase + (size_t)(h * 32 + srow) * S_LEN + k0 + scol,
              (char*)VT + h * 4096 + (size_t)tid * 16);
    }
    asm volatile("s_waitcnt vmcnt(0)" ::: "memory");
    __syncthreads();

    // --- S tile (16 q x 64 k) + exp -> P (wave-private LDS) ---
#pragma unroll
    for (int kt = 0; kt < 4; ++kt) {
      const int r = kt * 16 + l16;
      bf16x8 bk0 = *(const bf16x8*)(KT + r * 64 + 8 * (g ^ (r & 7)));
      bf16x8 bk1 = *(const bf16x8*)(KT + r * 64 + 8 * ((g + 4) ^ (r & 7)));
      f32x4 t = __builtin_amdgcn_mfma_f32_16x16x32_bf16(
          aq0, bk0, (f32x4){0.f, 0.f, 0.f, 0.f}, 0, 0, 0);
      t = __builtin_amdgcn_mfma_f32_16x16x32_bf16(aq1, bk1, t, 0, 0, 0);
#pragma unroll
      for (int r4 = 0; r4 < 4; ++r4)
        pl[g * 4 + r4][kt * 16 + l16] =
            (__bf16)__builtin_amdgcn_exp2f(t[r4] * C_EXP);
    }
    // --- P back as A-fragments (wave-private; no barrier) ---
    bf16x8 pa0 = *(const bf16x8*)(&pl[l16][g * 8]);
    bf16x8 pa1 = *(const bf16x8*)(&pl[l16][32 + g * 8]);
    // --- PV ---
#pragma unroll
    for (int dt = 0; dt < 4; ++dt) {
      const int rd = dt * 16 + l16;
      bf16x8 bv0 = *(const bf16x8*)(VT + rd * 64 + 8 * (g ^ (rd & 7)));
      bf16x8 bv1 = *(const bf16x8*)(VT + rd * 64 + 8 * ((g + 4) ^ (rd & 7)));
      acc[dt] = __builtin_amdgcn_mfma_f32_16x16x32_bf16(pa0, bv0, acc[dt], 0, 0, 0);
      acc[dt] = __builtin_amdgcn_mfma_f32_16x16x32_bf16(pa1, bv1, acc[dt], 0, 0, 0);
    }
  }
  // FIX (round 5): include the split-k slab offset (was racing on slab 0)
  float* ob = Op + ((size_t)ks * NB + b) * (size_t)(S_LEN * D_DIM);
#pragma unroll
  for (int dt = 0; dt < 4; ++dt)
#pragma unroll
    for (int r4 = 0; r4 < 4; ++r4)
      ob[(size_t)(qbase + g * 4 + r4) * D_DIM + dt * 16 + l16] = acc[dt][r4];
}

// ---------------------------------------------------------------------------
// Kernel E: reduce split-k partials (float4 vectorized, 1 elem/thread)
// ---------------------------------------------------------------------------
__global__ __launch_bounds__(256) void reduce_kernel(
    const float* __restrict__ Op, float* __restrict__ out, int np) {
  const int i = blockIdx.x * 256 + threadIdx.x;
  const int slab = NB * S_LEN * D_DIM / 4;  // float4 per slab
  const float4* p = (const float4*)Op;
  float4 s = p[i];
  for (int j = 1; j < np; ++j) {
    float4 t = p[i + (size_t)j * slab];
    s.x += t.x; s.y += t.y; s.z += t.z; s.w += t.w;
  }
  ((float4*)out)[i] = s;
}

// ---------------------------------------------------------------------------
extern "C" void kernel_launch(void* const* d_in, const int* in_sizes, int n_in,
                              void* d_out, int out_size, void* d_ws,
                              size_t ws_size, hipStream_t stream) {
  const float* q = (const float*)d_in[0];
  const float* k = (const float*)d_in[1];
  const float* v = (const float*)d_in[2];
  float* out = (float*)d_out;

  char* ws = (char*)d_ws;
  const size_t nelem = (size_t)NB * S_LEN * D_DIM;  // 2,097,152
  __bf16* Qb = (__bf16*)ws;                          // 4 MB @ 0
  __bf16* Kb = (__bf16*)(ws + nelem * 2);            // 4 MB @ 4M
  __bf16* Vt = (__bf16*)(ws + nelem * 4);            // 4 MB @ 8M
  float* Lp = (float*)(ws + nelem * 6);              // 512 KB @ 12M
  float* Op = (float*)(ws + (13u << 20));            // up to 32 MB @ 13M

  // split-k factor limited by workspace for fp32 partials
  int ksplit = 1;
  if (ws_size >= (13u << 20) + 4 * nelem * 4) ksplit = 4;
  else if (ws_size >= (13u << 20) + 2 * nelem * 4) ksplit = 2;

  convert_bf16_kernel<<<1024, 256, 0, stream>>>(q, k, Qb, Kb);
  stats_kernel<<<dim3(32, 16, 4), 256, 0, stream>>>(Qb, Kb, Lp, S_LEN / 4);
  scalev_kernel<<<dim3(8, 16), 256, 0, stream>>>(v, Lp, Vt);
  float* attn_dst = (ksplit == 1) ? out : Op;
  attn_out_kernel<<<dim3(32, 16, ksplit), 256, 0, stream>>>(Qb, Kb, Vt,
                                                            attn_dst,
                                                            S_LEN / ksplit);
  if (ksplit > 1)
    reduce_kernel<<<(int)(nelem / 4 / 256), 256, 0, stream>>>(Op, out, ksplit);
}